// Round 6
// baseline (184.766 us; speedup 1.0000x reference)
//
#include <hip/hip_runtime.h>

// NONA: out = softmax(-cdist(x, x_n), axis=1) @ y
//   x[4096,1024] f32, x_n[8192,1024] f32, y[8192,128] f32, log_T unused.
//
// R6 changes (R5 was LDS-read-BW bound: per-wave 32x64 tile = 0.75
// ds_read_b128/MFMA; 144 wave-reads/CU/K-round vs 233 cy MFMA/SIMD):
//  * square per-wave tiles: BM=256 x BN=64, 4 waves each 64x64 (R=C=4)
//    -> 0.5 reads/MFMA and 2x MFMA per staged byte. LDS = A-dbuf 64K +
//    B-dbuf 16K = 80K -> 2 blocks/CU; __launch_bounds__(256,2) (VGPR<=256).
//  * grid = 16 x split = 512 at split=32 (ws>=93MiB confirmed by R5 occ) =
//    exactly 2 blocks/CU, no tail.
//  * same T4 counted-vmcnt loop (vmcnt(10) for 8 A-loads + 2 B-loads);
//    V staged under the post-qk barrier, overlapping the exp tail.
//
// ws layout (bytes): xb@0 (8Mi) | xnb@8Mi (16Mi) | yT@24Mi (2Mi) |
//   xsq@26Mi (16Ki) | xnsq@+16Ki (32Ki) | Lpart@26Mi+48Ki (<=1Mi) |
//   Opart@28Mi (split*2Mi)

#define N_ 4096
#define M_ 8192
#define D_ 1024
#define C_ 128
#define BM 256
#define BN 64
#define BK 64
#define NKK (D_ / BK)        // 16

typedef __bf16 bf16;
typedef __attribute__((ext_vector_type(8))) __bf16 bf16x8;
typedef __attribute__((ext_vector_type(4))) __bf16 bf16x4;
typedef __attribute__((ext_vector_type(4))) float f32x4;

__device__ __forceinline__ void async_copy16(const bf16* gp, void* lp) {
  __builtin_amdgcn_global_load_lds(
      (__attribute__((address_space(1))) void*)const_cast<bf16*>(gp),
      (__attribute__((address_space(3))) void*)lp, 16, 0, 0);
}

// Swizzled LDS byte offset for a [rows][64]-bf16 tile (128 B rows):
// 16B-granule XOR with row&7. Staging stores src granule (g ^ row&7) at
// granule g (linear dest), so reading granule (g ^ row&7) returns src granule g.
__device__ __forceinline__ int swz(int row, int gran) {
  return (row << 7) + ((gran ^ (row & 7)) << 4);
}

// Stage NCH KiB-chunks of a [*][64]-bf16 tile global->LDS, source pre-swizzled.
// NCH=32 -> [256][64] (8 loads/thread); 16 -> [128][64]; 8 -> [64][64].
template <int NCH>
__device__ __forceinline__ void stage(const bf16* src, int ld, char* lds, int tid) {
  const int lane = tid & 63, wave = tid >> 6;
#pragma unroll
  for (int j = 0; j < NCH / 4; ++j) {
    const int ch  = j * 4 + wave;            // wave-uniform chunk id
    const int off = ch * 1024 + lane * 16;   // linear byte in tile
    const int row = off >> 7;
    const int grs = ((off >> 4) & 7) ^ (row & 7);
    async_copy16(src + (size_t)row * ld + grs * 8, lds + ch * 1024);
  }
}

__global__ __launch_bounds__(256, 2)
void nona_main(const bf16* __restrict__ xb, const bf16* __restrict__ xnb,
               const bf16* __restrict__ yT, const float* __restrict__ xsq,
               const float* __restrict__ xnsq, float* __restrict__ Opart,
               float* __restrict__ Lpart,
               int split_mask, int split_shift, int mcols, int nbn)
{
  __shared__ __align__(16) char Lds[81920];
  char* const A0 = Lds;            // x [256][64], even kk; tail: P [256][64]
  char* const A1 = Lds + 32768;    // x [256][64], odd kk
  char* const B0 = Lds + 65536;    // xn [64][64], even kk; tail: V [128 C][64] (B0+B1)
  char* const B1 = Lds + 73728;    // xn [64][64], odd kk

  const int tid  = threadIdx.x;
  const int lane = tid & 63;
  const int wave = tid >> 6;          // wave owns x rows wave*64..+64
  const int g = lane >> 4, c = lane & 15;

  const int bid  = blockIdx.x;
  const int s    = bid & split_mask;  // split id; bid%8 -> XCD round-robin locality
  const int rb   = bid >> split_shift;
  const int row0 = rb * BM;
  const int col0 = s * mcols;

  // swapped-S: lane's x rows are wave*64 + rf*16 + c (4 rows)
  float xs[4];
#pragma unroll
  for (int rf = 0; rf < 4; ++rf)
    xs[rf] = xsq[row0 + wave * 64 + rf * 16 + c];

  f32x4 Oacc[4][8];
  const f32x4 zero = {0.f, 0.f, 0.f, 0.f};
#pragma unroll
  for (int rf = 0; rf < 4; ++rf)
#pragma unroll
    for (int cc = 0; cc < 8; ++cc) Oacc[rf][cc] = zero;
  float lsum[4] = {0.f, 0.f, 0.f, 0.f};

  f32x4 Sacc[4][4];

  // S^T step: Sacc[rf][cf] = mfma(A = xn_frag, B = x_frag) ->
  // lane holds P[xn = cf*16 + g*4 + r][x = wave*64 + rf*16 + c]
  auto qkStep = [&](const char* Ac, const char* Bc) {
#pragma unroll
    for (int ks = 0; ks < 2; ++ks) {
      bf16x8 af[4];
#pragma unroll
      for (int rf = 0; rf < 4; ++rf)
        af[rf] = *(const bf16x8*)(Ac + swz(wave * 64 + rf * 16 + c, ks * 4 + g));
      __builtin_amdgcn_s_setprio(1);
#pragma unroll
      for (int cf = 0; cf < 4; ++cf) {
        bf16x8 bv = *(const bf16x8*)(Bc + swz(cf * 16 + c, ks * 4 + g));
#pragma unroll
        for (int rf = 0; rf < 4; ++rf)
          Sacc[rf][cf] = __builtin_amdgcn_mfma_f32_16x16x32_bf16(bv, af[rf], Sacc[rf][cf], 0, 0, 0);
      }
      __builtin_amdgcn_s_setprio(0);
    }
  };

  for (int bn = 0; bn < nbn; ++bn) {
    const int colbase = col0 + bn * BN;
    const bf16* xA = xb + (size_t)row0 * D_;
    const bf16* xB = xnb + (size_t)colbase * D_;

#pragma unroll
    for (int rf = 0; rf < 4; ++rf)
#pragma unroll
      for (int cf = 0; cf < 4; ++cf) Sacc[rf][cf] = zero;

    __syncthreads();                 // prev bn's PV readers of A0(P)/B(V) done; vm=0
    stage<32>(xA, D_, A0, tid);      // stage(0): 10 loads/thread
    stage<8>(xB, D_, B0, tid);

#pragma unroll 1
    for (int kk = 0; kk < NKK - 1; ++kk) {
      // WAR: buf[(kk+1)&1] last read at qkStep(kk-1), protected by bar2 below.
      stage<32>(xA + (kk + 1) * BK, D_, (kk & 1) ? A0 : A1, tid);
      stage<8>(xB + (kk + 1) * BK, D_, (kk & 1) ? B0 : B1, tid);
      asm volatile("s_waitcnt vmcnt(10)" ::: "memory");  // own stage(kk) landed
      __builtin_amdgcn_s_barrier();                      // bar1: all stage(kk) landed
      __builtin_amdgcn_sched_barrier(0);
      qkStep((kk & 1) ? A1 : A0, (kk & 1) ? B1 : B0);
      __builtin_amdgcn_sched_barrier(0);
      __builtin_amdgcn_s_barrier();                      // bar2: buf[kk&1] reads done
    }
    // peeled kk = 15 (odd): compute A1/B1
    asm volatile("s_waitcnt vmcnt(0)" ::: "memory");     // stage(15) landed
    __builtin_amdgcn_s_barrier();
    __builtin_amdgcn_sched_barrier(0);
    qkStep(A1, B1);
    __builtin_amdgcn_s_barrier();    // all waves done reading A1/B1 (own reads
                                     // consumed by issued MFMAs; cross-wave by barrier)
    stage<16>(yT + colbase, M_, B0, tid);   // V [128C][64] -> B0+B1 (in flight)

    // elementwise (overlaps V flight): w = exp(-sqrt(max(xsq+xnsq-2dot,0)))
#pragma unroll
    for (int cf = 0; cf < 4; ++cf) {
      const float4 nsq4 = *(const float4*)(xnsq + colbase + cf * 16 + g * 4);
#pragma unroll
      for (int rf = 0; rf < 4; ++rf)
#pragma unroll
        for (int r = 0; r < 4; ++r) {
          float d2 = xs[rf] + ((const float*)&nsq4)[r] - 2.0f * Sacc[rf][cf][r];
          d2 = fmaxf(d2, 0.0f);
          const float wv = __expf(-sqrtf(d2));
          lsum[rf] += wv;
          Sacc[rf][cf][r] = wv;     // reuse Sacc as w storage
        }
    }

    // P-write -> A0 [256][64] (A0 dead since kk=14 bar2, all waves past it):
    // lane writes 4 consecutive xn (8 B) per (rf,cf): ds_write_b64
#pragma unroll
    for (int rf = 0; rf < 4; ++rf)
#pragma unroll
      for (int cf = 0; cf < 4; ++cf) {
        bf16x4 pk;
#pragma unroll
        for (int r = 0; r < 4; ++r) pk[r] = (bf16)Sacc[rf][cf][r];
        const int row  = wave * 64 + rf * 16 + c;
        const int gi   = 2 * cf + (g >> 1);
        const int byte = (row << 7) + ((gi ^ (row & 7)) << 4) + 8 * (g & 1);
        *(bf16x4*)(A0 + byte) = pk;
      }
    __syncthreads();   // drains vmcnt(0): V landed; P visible
    // PV: O[64 x 128C] += P[64 x 64] @ V^T (V stored [128C][64] at B0)
#pragma unroll
    for (int ks = 0; ks < 2; ++ks) {
      bf16x8 pa[4];
#pragma unroll
      for (int rf = 0; rf < 4; ++rf)
        pa[rf] = *(const bf16x8*)(A0 + swz(wave * 64 + rf * 16 + c, ks * 4 + g));
      __builtin_amdgcn_s_setprio(1);
#pragma unroll
      for (int cc = 0; cc < 8; ++cc) {
        bf16x8 vb = *(const bf16x8*)(B0 + swz(cc * 16 + c, ks * 4 + g));
#pragma unroll
        for (int rf = 0; rf < 4; ++rf)
          Oacc[rf][cc] = __builtin_amdgcn_mfma_f32_16x16x32_bf16(pa[rf], vb, Oacc[rf][cc], 0, 0, 0);
      }
      __builtin_amdgcn_s_setprio(0);
    }
    // next bn's prologue __syncthreads protects A0/A1/B restage vs PV readers
  }

  // ---- epilogue: per-row l: rows with same c live in lanes {c,c+16,c+32,c+48}
#pragma unroll
  for (int rf = 0; rf < 4; ++rf) {
    float v = lsum[rf];
    v += __shfl_xor(v, 16);
    v += __shfl_xor(v, 32);
    if (g == 0)
      Lpart[(size_t)s * N_ + row0 + wave * 64 + rf * 16 + c] = v;
  }

  float* ob = Opart + ((size_t)s * N_ + row0) * C_;
#pragma unroll
  for (int rf = 0; rf < 4; ++rf)
#pragma unroll
    for (int cc = 0; cc < 8; ++cc)
#pragma unroll
      for (int r = 0; r < 4; ++r)
        ob[(wave * 64 + rf * 16 + g * 4 + r) * C_ + cc * 16 + c] = Oacc[rf][cc][r];
}

// row-wise: f32 -> bf16 copy + exact f32 squared norm
__global__ void prep_rows(const float* __restrict__ src, bf16* __restrict__ dst,
                          float* __restrict__ sq)
{
  const int row = blockIdx.x;
  const int t = threadIdx.x;                   // 256 threads, 4 f32 each
  const float4 v = reinterpret_cast<const float4*>(src + (size_t)row * D_)[t];
  float ss = v.x * v.x + v.y * v.y + v.z * v.z + v.w * v.w;
  bf16x4 hv;
  hv[0] = (bf16)v.x; hv[1] = (bf16)v.y; hv[2] = (bf16)v.z; hv[3] = (bf16)v.w;
  *reinterpret_cast<bf16x4*>(dst + (size_t)row * D_ + t * 4) = hv;
#pragma unroll
  for (int o = 32; o > 0; o >>= 1) ss += __shfl_down(ss, o);
  __shared__ float red[4];
  if ((t & 63) == 0) red[t >> 6] = ss;
  __syncthreads();
  if (t == 0) sq[row] = red[0] + red[1] + red[2] + red[3];
}

// y[8192][128] f32 -> yT[128][8192] bf16
__global__ void prep_yT(const float* __restrict__ y, bf16* __restrict__ yT)
{
  __shared__ bf16 tile[C_][72];
  const int m0 = blockIdx.x * 64;
  const int t = threadIdx.x;
#pragma unroll
  for (int i = 0; i < 32; ++i) {
    const int idx = i * 256 + t;               // 0..8191
    const int ml = idx >> 7, cc = idx & 127;
    tile[cc][ml] = (bf16)y[(size_t)(m0 + ml) * C_ + cc];
  }
  __syncthreads();
#pragma unroll
  for (int i = 0; i < 32; ++i) {
    const int idx = i * 256 + t;
    const int cc = idx >> 6, ml = idx & 63;
    yT[(size_t)cc * M_ + m0 + ml] = tile[cc][ml];
  }
}

__global__ void combine(const float* __restrict__ Opart, const float* __restrict__ Lpart,
                        float* __restrict__ out, int split)
{
  const int i = blockIdx.x * 256 + threadIdx.x;   // < N_*C_
  const int row = i >> 7;
  float o = 0.f, l = 0.f;
  for (int s = 0; s < split; ++s) {
    o += Opart[(size_t)s * N_ * C_ + i];
    l += Lpart[(size_t)s * N_ + row];
  }
  out[i] = o / l;
}

extern "C" void kernel_launch(void* const* d_in, const int* in_sizes, int n_in,
                              void* d_out, int out_size, void* d_ws, size_t ws_size,
                              hipStream_t stream)
{
  const float* x  = (const float*)d_in[0];
  const float* xn = (const float*)d_in[1];
  const float* y  = (const float*)d_in[2];
  // d_in[3] = log_T: computed-but-unused in the reference forward.
  float* out = (float*)d_out;

  char* ws = (char*)d_ws;
  bf16*  xb    = (bf16*)(ws);
  bf16*  xnb   = (bf16*)(ws + (size_t)8  * 1024 * 1024);
  bf16*  yT    = (bf16*)(ws + (size_t)24 * 1024 * 1024);
  float* xsq   = (float*)(ws + (size_t)26 * 1024 * 1024);
  float* xnsq  = (float*)(ws + (size_t)26 * 1024 * 1024 + 16 * 1024);
  float* Lpart = (float*)(ws + (size_t)26 * 1024 * 1024 + 48 * 1024);
  float* Opart = (float*)(ws + (size_t)28 * 1024 * 1024);

  // choose split count by available workspace: Opart = split * 2 MiB @ 28 MiB
  int split, shift;
  const size_t MB = 1024 * 1024;
  if      (ws_size >= 157 * MB) { split = 64; shift = 6; }
  else if (ws_size >= 93  * MB) { split = 32; shift = 5; }
  else if (ws_size >= 61  * MB) { split = 16; shift = 4; }
  else                          { split = 8;  shift = 3; }
  const int mcols = M_ / split;
  const int nbn   = mcols / BN;

  prep_rows<<<N_, 256, 0, stream>>>(x, xb, xsq);
  prep_rows<<<M_, 256, 0, stream>>>(xn, xnb, xnsq);
  prep_yT<<<M_ / 64, 256, 0, stream>>>(y, yT);
  nona_main<<<(N_ / BM) * split, 256, 0, stream>>>(xb, xnb, yT, xsq, xnsq, Opart, Lpart,
                                                   split - 1, shift, mcols, nbn);
  combine<<<(N_ * C_) / 256, 256, 0, stream>>>(Opart, Lpart, out, split);
}